// Round 23
// baseline (460.988 us; speedup 1.0000x reference)
//
#include <hip/hip_runtime.h>
#include <stdint.h>

// 2-layer LSTM, B=64, T=1024, D=512, H=32, fp32 in/out.
// Phase 1: f16 MFMA GEMM (proven R14, ~30us).
// Phase 2: barrier-systolic 3-wave scan, ONE timestep per barrier (R21 = 381us)
//   with ONE isolated change (R22 post-mortem: 2-step phases were the bug):
//   closed-loop waves (w0, w2) keep their own h-state in REGISTERS via
//   readlane at the step TAIL (overlaps barrier wait) instead of a
//   post-barrier LDS load at the step HEAD (~120cy on critical path).
//   w2 loads PIA/PIB early (hidden under its Whh1 dots). H1R ring deleted.

#define TT 1024
#define BB 64
#define DD 512
#define HH 32
#define GG 128   // 4*H

typedef _Float16 h2v __attribute__((ext_vector_type(2)));
typedef __fp16 pk2 __attribute__((ext_vector_type(2)));
typedef int int2v __attribute__((ext_vector_type(2)));
typedef _Float16 f16x8 __attribute__((ext_vector_type(8)));
typedef float f32x4 __attribute__((ext_vector_type(4)));

__device__ __forceinline__ uint32_t pack2(float lo, float hi) {
  pk2 p = __builtin_amdgcn_cvt_pkrtz(lo, hi);
  return __builtin_bit_cast(uint32_t, p);
}
__device__ __forceinline__ float dot2(uint32_t a, uint32_t b, float acc) {
  return __builtin_amdgcn_fdot2(__builtin_bit_cast(h2v, a),
                                __builtin_bit_cast(h2v, b), acc, false);
}
__device__ __forceinline__ float fast_rcp(float x) { return __builtin_amdgcn_rcpf(x); }
__device__ __forceinline__ float sigm(float s) { return fast_rcp(1.f + __expf(-s)); }
__device__ __forceinline__ float fast_tanh(float x) {
  return fmaf(2.f, fast_rcp(1.f + __expf(-2.f * x)), -1.f);
}
__device__ __forceinline__ float act_sel(float s, bool ist) {
  float z = ist ? s + s : s;
  float r = fast_rcp(1.f + __expf(-z));
  return ist ? fmaf(2.f, r, -1.f) : r;
}

// xor-32 partner, pure VALU; order-proof XOR extraction (verified R6).
__device__ __forceinline__ float partner32(float x) {
  int xi = __builtin_bit_cast(int, x);
#if __has_builtin(__builtin_amdgcn_permlane32_swap)
  int2v r = __builtin_amdgcn_permlane32_swap(xi, xi, false, false);
  return __builtin_bit_cast(float, r.x ^ r.y ^ xi);
#else
  int a = xi, b = xi;
  asm("v_permlane32_swap_b32 %0, %1" : "+v"(a), "+v"(b));
  return __builtin_bit_cast(float, a ^ b ^ xi);
#endif
}

// xor-1 neighbor exchange via DPP quad_perm [1,0,3,2]
__device__ __forceinline__ float xor1_dpp(float x) {
  int xi = __builtin_bit_cast(int, x);
  int r = __builtin_amdgcn_update_dpp(xi, xi, 0xB1, 0xF, 0xF, true);
  return __builtin_bit_cast(float, r);
}

// ---------------- Phase 1: f16 MFMA GEMM (proven R14) ----------------
__global__ __launch_bounds__(256) void xg_gemm_mfma(const float* __restrict__ x,
                                                    const float* __restrict__ W,
                                                    const float* __restrict__ bih,
                                                    const float* __restrict__ bhh,
                                                    float* __restrict__ outp) {
  __shared__ _Float16 lxs[128][40];
  __shared__ _Float16 lws[128][40];
  const int tid = threadIdx.x;
  const int m0 = blockIdx.x * 128;
  const int sr = tid >> 1;
  const int sk = (tid & 1) * 16;
  const int w = tid >> 6;
  const int wm = (w >> 1) * 64;
  const int wn = (w & 1) * 64;
  const int lane = tid & 63;
  const int lr = lane & 15;
  const int lk = (lane >> 4) * 8;

  f32x4 acc[4][4];
#pragma unroll
  for (int i = 0; i < 4; ++i)
#pragma unroll
    for (int j = 0; j < 4; ++j) acc[i][j] = (f32x4){0.f, 0.f, 0.f, 0.f};

  for (int k0 = 0; k0 < DD; k0 += 32) {
#pragma unroll
    for (int c = 0; c < 4; ++c) {
      const float4 xv = *(const float4*)(x + (size_t)(m0 + sr) * DD + k0 + sk + c * 4);
      uint2 px;
      px.x = pack2(xv.x, xv.y);
      px.y = pack2(xv.z, xv.w);
      *(uint2*)&lxs[sr][sk + c * 4] = px;
      const float4 wv = *(const float4*)(W + (size_t)sr * DD + k0 + sk + c * 4);
      uint2 pw;
      pw.x = pack2(wv.x, wv.y);
      pw.y = pack2(wv.z, wv.w);
      *(uint2*)&lws[sr][sk + c * 4] = pw;
    }
    __syncthreads();
    f16x8 af[4], bf[4];
#pragma unroll
    for (int s = 0; s < 4; ++s) {
      af[s] = *(const f16x8*)&lxs[wm + s * 16 + lr][lk];
      bf[s] = *(const f16x8*)&lws[wn + s * 16 + lr][lk];
    }
#pragma unroll
    for (int mi = 0; mi < 4; ++mi)
#pragma unroll
      for (int ni = 0; ni < 4; ++ni)
        acc[mi][ni] = __builtin_amdgcn_mfma_f32_16x16x32_f16(af[mi], bf[ni],
                                                             acc[mi][ni], 0, 0, 0);
    __syncthreads();
  }
  const int rq = (lane >> 4) * 4;
#pragma unroll
  for (int ni = 0; ni < 4; ++ni) {
    const int g = wn + ni * 16 + lr;
    const float bsum = bih[g] + bhh[g];
#pragma unroll
    for (int mi = 0; mi < 4; ++mi) {
      const int mbase = m0 + wm + mi * 16 + rq;
#pragma unroll
      for (int q = 0; q < 4; ++q)
        outp[(size_t)(mbase + q) * GG + g] = acc[mi][ni][q] + bsum;
    }
  }
}

__device__ __forceinline__ void load16(const uint32_t* p, uint32_t* v) {
  uint4 r0 = ((const uint4*)p)[0];
  uint4 r1 = ((const uint4*)p)[1];
  uint4 r2 = ((const uint4*)p)[2];
  uint4 r3 = ((const uint4*)p)[3];
  v[0] = r0.x; v[1] = r0.y; v[2] = r0.z; v[3] = r0.w;
  v[4] = r1.x; v[5] = r1.y; v[6] = r1.z; v[7] = r1.w;
  v[8] = r2.x; v[9] = r2.y; v[10] = r2.z; v[11] = r2.w;
  v[12] = r3.x; v[13] = r3.y; v[14] = r3.z; v[15] = r3.w;
}

// ---------------- Phase 2: barrier-systolic 3-wave scan (reg-resident h) ----
__global__ __launch_bounds__(192)
void lstm_scan_sys(const float* __restrict__ xg,
                   const float* __restrict__ Whh0,
                   const float* __restrict__ Wih1,
                   const float* __restrict__ Whh1,
                   const float* __restrict__ bih1,
                   const float* __restrict__ bhh1,
                   float* __restrict__ out) {
  __shared__ alignas(16) uint32_t H0R[4][16];  // packed-f16 h0 ring (for w1)
  __shared__ alignas(16) float PIA[4][64];     // b1A + Wih1[gA]*h0
  __shared__ alignas(16) float PIB[4][64];     // b1B + Wih1[gB]*h0

  const int tid = threadIdx.x;
  const int wid = tid >> 6;
  const int l = tid & 63;
  const int j = l & 31;
  const int hi = l >> 5;
  const int b = blockIdx.x;
  const int gA = j + 64 * hi;   // i (hi=0) / g (hi=1) gate
  const int gB = gA + 32;       // f (hi=0) / o (hi=1) gate
  const bool wrt = (!hi) && ((j & 1) == 0);  // 16 writer lanes

  uint32_t wA[16], wB[16];   // role-specific weights
  float b1A = 0.f, b1B = 0.f;
  float cc = 0.f;            // c0 (w0) or c1 (w2)
  uint32_t hreg[16];         // w0: h0[s-1]; w2: h1[tau-1] (wave-uniform)
#pragma unroll
  for (int k = 0; k < 16; ++k) hreg[k] = 0u;

  const float* xgp = xg + (size_t)b * TT * GG;
  float* outp = out + (size_t)b * TT * HH;
  float xA[4], xB[4];

  if (wid == 0) {
#pragma unroll
    for (int q = 0; q < 8; ++q) {
      float4 a = *(const float4*)(Whh0 + (size_t)gA * HH + q * 4);
      float4 c = *(const float4*)(Whh0 + (size_t)gB * HH + q * 4);
      wA[2 * q] = pack2(a.x, a.y); wA[2 * q + 1] = pack2(a.z, a.w);
      wB[2 * q] = pack2(c.x, c.y); wB[2 * q + 1] = pack2(c.z, c.w);
    }
#pragma unroll
    for (int u = 0; u < 4; ++u) {
      xA[u] = xgp[u * GG + gA];
      xB[u] = xgp[u * GG + gB];
    }
  } else if (wid == 1) {
#pragma unroll
    for (int q = 0; q < 8; ++q) {
      float4 d = *(const float4*)(Wih1 + (size_t)gA * HH + q * 4);
      float4 e = *(const float4*)(Wih1 + (size_t)gB * HH + q * 4);
      wA[2 * q] = pack2(d.x, d.y); wA[2 * q + 1] = pack2(d.z, d.w);
      wB[2 * q] = pack2(e.x, e.y); wB[2 * q + 1] = pack2(e.z, e.w);
    }
    b1A = bih1[gA] + bhh1[gA];
    b1B = bih1[gB] + bhh1[gB];
  } else {
#pragma unroll
    for (int q = 0; q < 8; ++q) {
      float4 f = *(const float4*)(Whh1 + (size_t)gA * HH + q * 4);
      float4 g = *(const float4*)(Whh1 + (size_t)gB * HH + q * 4);
      wA[2 * q] = pack2(f.x, f.y); wA[2 * q + 1] = pack2(f.z, f.w);
      wB[2 * q] = pack2(g.x, g.y); wB[2 * q + 1] = pack2(g.z, g.w);
    }
  }
  __syncthreads();

  for (int s = 0; s < TT + 2; ++s) {
    if (wid == 0) {
      if (s < TT) {
        // ---- layer0 closed loop: h0[s] from hreg (= h0[s-1]) ----
        float sA0 = xA[s & 3], sB0 = xB[s & 3];
        const int tp = (s + 4 < TT) ? (s + 4) : (TT - 1);
        xA[s & 3] = xgp[(size_t)tp * GG + gA];
        xB[s & 3] = xgp[(size_t)tp * GG + gB];
        float pA = 0.f, pB = 0.f;
#pragma unroll
        for (int k = 0; k < 16; k += 2) {
          sA0 = dot2(wA[k], hreg[k], sA0);
          pA  = dot2(wA[k + 1], hreg[k + 1], pA);
          sB0 = dot2(wB[k], hreg[k], sB0);
          pB  = dot2(wB[k + 1], hreg[k + 1], pB);
        }
        sA0 += pA; sB0 += pB;
        float aA = act_sel(sA0, hi != 0);
        float aB = sigm(sB0);
        float pAx = partner32(aA);
        float pBx = partner32(aB);
        float gi = hi ? pAx : aA;
        float gf = hi ? pBx : aB;
        float gg = hi ? aA : pAx;
        float go = hi ? aB : pBx;
        cc = fmaf(gf, cc, gi * gg);
        float h = go * fast_tanh(cc);
        float oth = xor1_dpp(h);
        float lo = (j & 1) ? oth : h;
        float hh = (j & 1) ? h : oth;
        uint32_t pk = pack2(lo, hh);
        if (wrt) H0R[s & 3][j >> 1] = pk;  // for w1
        // tail broadcast: issue overlaps upcoming barrier wait
#pragma unroll
        for (int m = 0; m < 16; ++m)
          hreg[m] = (uint32_t)__builtin_amdgcn_readlane((int)pk, 2 * m);
      }
    } else if (wid == 1) {
      if (s >= 1 && s <= TT) {
        // ---- PIH[tau] = b1 + Wih1*h0[tau], tau = s-1 (reads H0R) ----
        const int tau = s - 1;
        uint32_t h0v[16];
        load16(&H0R[tau & 3][0], h0v);
        float a0 = b1A, a1 = 0.f, b0 = b1B, b1v = 0.f;
#pragma unroll
        for (int k = 0; k < 16; k += 2) {
          a0 = dot2(wA[k], h0v[k], a0);
          a1 = dot2(wA[k + 1], h0v[k + 1], a1);
          b0 = dot2(wB[k], h0v[k], b0);
          b1v = dot2(wB[k + 1], h0v[k + 1], b1v);
        }
        PIA[tau & 3][l] = a0 + a1;
        PIB[tau & 3][l] = b0 + b1v;
      }
    } else {
      if (s >= 2) {
        // ---- layer1 closed loop for tau = s-2; h1 prev in hreg ----
        const int tau = s - 2;
        // issue PIA/PIB loads first (independent of dots; latency hidden)
        const float prAv = PIA[tau & 3][l];
        const float prBv = PIB[tau & 3][l];
        float rA = 0.f, qA = 0.f, rB = 0.f, qB = 0.f;
#pragma unroll
        for (int k = 0; k < 16; k += 2) {
          rA = dot2(wA[k], hreg[k], rA);
          qA = dot2(wA[k + 1], hreg[k + 1], qA);
          rB = dot2(wB[k], hreg[k], rB);
          qB = dot2(wB[k + 1], hreg[k + 1], qB);
        }
        const float sA1 = prAv + rA + qA;
        const float sB1 = prBv + rB + qB;
        float aA = act_sel(sA1, hi != 0);
        float aB = sigm(sB1);
        float pAx = partner32(aA);
        float pBx = partner32(aB);
        float gi = hi ? pAx : aA;
        float gf = hi ? pBx : aB;
        float gg = hi ? aA : pAx;
        float go = hi ? aB : pBx;
        cc = fmaf(gf, cc, gi * gg);
        float h = go * fast_tanh(cc);
        if (!hi) outp[(size_t)tau * HH + j] = h;
        float oth = xor1_dpp(h);
        float lo = (j & 1) ? oth : h;
        float hh = (j & 1) ? h : oth;
        uint32_t pk = pack2(lo, hh);
#pragma unroll
        for (int m = 0; m < 16; ++m)
          hreg[m] = (uint32_t)__builtin_amdgcn_readlane((int)pk, 2 * m);
      }
    }
    __syncthreads();
  }
}

extern "C" void kernel_launch(void* const* d_in, const int* in_sizes, int n_in,
                              void* d_out, int out_size, void* d_ws, size_t ws_size,
                              hipStream_t stream) {
  const float* x = (const float*)d_in[0];
  const float* Wih0 = (const float*)d_in[1];
  const float* Whh0 = (const float*)d_in[2];
  const float* bih0 = (const float*)d_in[3];
  const float* bhh0 = (const float*)d_in[4];
  const float* Wih1 = (const float*)d_in[5];
  const float* Whh1 = (const float*)d_in[6];
  const float* bih1 = (const float*)d_in[7];
  const float* bhh1 = (const float*)d_in[8];
  float* out = (float*)d_out;
  float* xg = (float*)d_ws;  // B*T*4H*4 = 33.5 MB scratch

  xg_gemm_mfma<<<dim3((BB * TT) / 128), dim3(256), 0, stream>>>(x, Wih0, bih0, bhh0, xg);
  lstm_scan_sys<<<dim3(BB), dim3(192), 0, stream>>>(xg, Whh0, Wih1, Whh1, bih1, bhh1, out);
}

// Round 24
// 410.752 us; speedup vs baseline: 1.1223x; 1.1223x over previous
//
#include <hip/hip_runtime.h>
#include <stdint.h>

// 2-layer LSTM, B=64, T=1024, D=512, H=32, fp32 in/out.
// Phase 1: f16 MFMA GEMM (proven R14, ~30us).
// Phase 2: barrier-systolic 3-wave scan, 64 blocks x 192 threads. (R21 BEST:
//   scan 381us, total 411us. R22 2-step phases: -34us. R23 readlane-tail:
//   -50us. This exact configuration is the measured local optimum.)
//   One __syncthreads per timestep; rings indexed s&3; roles offset in time:
//     w0 @ s: layer0 closed loop  -> H0R[s]      (reads H0R[s-1])
//     w1 @ s: PIH[s-1] = b1 + Wih1*h0[s-1]       (reads H0R[s-1])
//     w2 @ s: layer1 closed loop for tau=s-2     (reads PIH[tau], H1R[tau-1])

#define TT 1024
#define BB 64
#define DD 512
#define HH 32
#define GG 128   // 4*H

typedef _Float16 h2v __attribute__((ext_vector_type(2)));
typedef __fp16 pk2 __attribute__((ext_vector_type(2)));
typedef int int2v __attribute__((ext_vector_type(2)));
typedef _Float16 f16x8 __attribute__((ext_vector_type(8)));
typedef float f32x4 __attribute__((ext_vector_type(4)));

__device__ __forceinline__ uint32_t pack2(float lo, float hi) {
  pk2 p = __builtin_amdgcn_cvt_pkrtz(lo, hi);
  return __builtin_bit_cast(uint32_t, p);
}
__device__ __forceinline__ float dot2(uint32_t a, uint32_t b, float acc) {
  return __builtin_amdgcn_fdot2(__builtin_bit_cast(h2v, a),
                                __builtin_bit_cast(h2v, b), acc, false);
}
__device__ __forceinline__ float fast_rcp(float x) { return __builtin_amdgcn_rcpf(x); }
__device__ __forceinline__ float sigm(float s) { return fast_rcp(1.f + __expf(-s)); }
__device__ __forceinline__ float fast_tanh(float x) {
  return fmaf(2.f, fast_rcp(1.f + __expf(-2.f * x)), -1.f);
}
__device__ __forceinline__ float act_sel(float s, bool ist) {
  float z = ist ? s + s : s;
  float r = fast_rcp(1.f + __expf(-z));
  return ist ? fmaf(2.f, r, -1.f) : r;
}

// xor-32 partner, pure VALU; order-proof XOR extraction (verified R6).
__device__ __forceinline__ float partner32(float x) {
  int xi = __builtin_bit_cast(int, x);
#if __has_builtin(__builtin_amdgcn_permlane32_swap)
  int2v r = __builtin_amdgcn_permlane32_swap(xi, xi, false, false);
  return __builtin_bit_cast(float, r.x ^ r.y ^ xi);
#else
  int a = xi, b = xi;
  asm("v_permlane32_swap_b32 %0, %1" : "+v"(a), "+v"(b));
  return __builtin_bit_cast(float, a ^ b ^ xi);
#endif
}

// xor-1 neighbor exchange via DPP quad_perm [1,0,3,2]
__device__ __forceinline__ float xor1_dpp(float x) {
  int xi = __builtin_bit_cast(int, x);
  int r = __builtin_amdgcn_update_dpp(xi, xi, 0xB1, 0xF, 0xF, true);
  return __builtin_bit_cast(float, r);
}

// ---------------- Phase 1: f16 MFMA GEMM (proven R14) ----------------
__global__ __launch_bounds__(256) void xg_gemm_mfma(const float* __restrict__ x,
                                                    const float* __restrict__ W,
                                                    const float* __restrict__ bih,
                                                    const float* __restrict__ bhh,
                                                    float* __restrict__ outp) {
  __shared__ _Float16 lxs[128][40];
  __shared__ _Float16 lws[128][40];
  const int tid = threadIdx.x;
  const int m0 = blockIdx.x * 128;
  const int sr = tid >> 1;
  const int sk = (tid & 1) * 16;
  const int w = tid >> 6;
  const int wm = (w >> 1) * 64;
  const int wn = (w & 1) * 64;
  const int lane = tid & 63;
  const int lr = lane & 15;
  const int lk = (lane >> 4) * 8;

  f32x4 acc[4][4];
#pragma unroll
  for (int i = 0; i < 4; ++i)
#pragma unroll
    for (int j = 0; j < 4; ++j) acc[i][j] = (f32x4){0.f, 0.f, 0.f, 0.f};

  for (int k0 = 0; k0 < DD; k0 += 32) {
#pragma unroll
    for (int c = 0; c < 4; ++c) {
      const float4 xv = *(const float4*)(x + (size_t)(m0 + sr) * DD + k0 + sk + c * 4);
      uint2 px;
      px.x = pack2(xv.x, xv.y);
      px.y = pack2(xv.z, xv.w);
      *(uint2*)&lxs[sr][sk + c * 4] = px;
      const float4 wv = *(const float4*)(W + (size_t)sr * DD + k0 + sk + c * 4);
      uint2 pw;
      pw.x = pack2(wv.x, wv.y);
      pw.y = pack2(wv.z, wv.w);
      *(uint2*)&lws[sr][sk + c * 4] = pw;
    }
    __syncthreads();
    f16x8 af[4], bf[4];
#pragma unroll
    for (int s = 0; s < 4; ++s) {
      af[s] = *(const f16x8*)&lxs[wm + s * 16 + lr][lk];
      bf[s] = *(const f16x8*)&lws[wn + s * 16 + lr][lk];
    }
#pragma unroll
    for (int mi = 0; mi < 4; ++mi)
#pragma unroll
      for (int ni = 0; ni < 4; ++ni)
        acc[mi][ni] = __builtin_amdgcn_mfma_f32_16x16x32_f16(af[mi], bf[ni],
                                                             acc[mi][ni], 0, 0, 0);
    __syncthreads();
  }
  const int rq = (lane >> 4) * 4;
#pragma unroll
  for (int ni = 0; ni < 4; ++ni) {
    const int g = wn + ni * 16 + lr;
    const float bsum = bih[g] + bhh[g];
#pragma unroll
    for (int mi = 0; mi < 4; ++mi) {
      const int mbase = m0 + wm + mi * 16 + rq;
#pragma unroll
      for (int q = 0; q < 4; ++q)
        outp[(size_t)(mbase + q) * GG + g] = acc[mi][ni][q] + bsum;
    }
  }
}

__device__ __forceinline__ void load16(const uint32_t* p, uint32_t* v) {
  uint4 r0 = ((const uint4*)p)[0];
  uint4 r1 = ((const uint4*)p)[1];
  uint4 r2 = ((const uint4*)p)[2];
  uint4 r3 = ((const uint4*)p)[3];
  v[0] = r0.x; v[1] = r0.y; v[2] = r0.z; v[3] = r0.w;
  v[4] = r1.x; v[5] = r1.y; v[6] = r1.z; v[7] = r1.w;
  v[8] = r2.x; v[9] = r2.y; v[10] = r2.z; v[11] = r2.w;
  v[12] = r3.x; v[13] = r3.y; v[14] = r3.z; v[15] = r3.w;
}

// ---------------- Phase 2: barrier-systolic 3-wave scan ----------------
__global__ __launch_bounds__(192)
void lstm_scan_sys(const float* __restrict__ xg,
                   const float* __restrict__ Whh0,
                   const float* __restrict__ Wih1,
                   const float* __restrict__ Whh1,
                   const float* __restrict__ bih1,
                   const float* __restrict__ bhh1,
                   float* __restrict__ out) {
  __shared__ alignas(16) uint32_t H0R[4][16];  // packed-f16 h0 ring
  __shared__ alignas(16) uint32_t H1R[4][16];  // packed-f16 h1 ring
  __shared__ alignas(16) float PIA[4][64];     // b1A + Wih1[gA]*h0
  __shared__ alignas(16) float PIB[4][64];     // b1B + Wih1[gB]*h0

  const int tid = threadIdx.x;
  const int wid = tid >> 6;
  const int l = tid & 63;
  const int j = l & 31;
  const int hi = l >> 5;
  const int b = blockIdx.x;
  const int gA = j + 64 * hi;   // i (hi=0) / g (hi=1) gate
  const int gB = gA + 32;       // f (hi=0) / o (hi=1) gate
  const bool wrt = (!hi) && ((j & 1) == 0);  // 16 writer lanes

  // zero rings (h0[-1]=0, h1[-1]=0)
  if (tid < 64) {
    H0R[tid >> 4][tid & 15] = 0u;
    H1R[tid >> 4][tid & 15] = 0u;
  }
  __syncthreads();

  // ---- per-role persistent state ----
  uint32_t wA[16], wB[16];   // role-specific weight set
  float b1A = 0.f, b1B = 0.f;
  float cc = 0.f;            // c0 (w0) or c1 (w2)
  const float* xgp = xg + (size_t)b * TT * GG;
  float* outp = out + (size_t)b * TT * HH;
  float xA[4], xB[4];

  if (wid == 0) {
#pragma unroll
    for (int q = 0; q < 8; ++q) {
      float4 a = *(const float4*)(Whh0 + (size_t)gA * HH + q * 4);
      float4 c = *(const float4*)(Whh0 + (size_t)gB * HH + q * 4);
      wA[2 * q] = pack2(a.x, a.y); wA[2 * q + 1] = pack2(a.z, a.w);
      wB[2 * q] = pack2(c.x, c.y); wB[2 * q + 1] = pack2(c.z, c.w);
    }
#pragma unroll
    for (int u = 0; u < 4; ++u) {
      xA[u] = xgp[u * GG + gA];
      xB[u] = xgp[u * GG + gB];
    }
  } else if (wid == 1) {
#pragma unroll
    for (int q = 0; q < 8; ++q) {
      float4 d = *(const float4*)(Wih1 + (size_t)gA * HH + q * 4);
      float4 e = *(const float4*)(Wih1 + (size_t)gB * HH + q * 4);
      wA[2 * q] = pack2(d.x, d.y); wA[2 * q + 1] = pack2(d.z, d.w);
      wB[2 * q] = pack2(e.x, e.y); wB[2 * q + 1] = pack2(e.z, e.w);
    }
    b1A = bih1[gA] + bhh1[gA];
    b1B = bih1[gB] + bhh1[gB];
  } else {
#pragma unroll
    for (int q = 0; q < 8; ++q) {
      float4 f = *(const float4*)(Whh1 + (size_t)gA * HH + q * 4);
      float4 g = *(const float4*)(Whh1 + (size_t)gB * HH + q * 4);
      wA[2 * q] = pack2(f.x, f.y); wA[2 * q + 1] = pack2(f.z, f.w);
      wB[2 * q] = pack2(g.x, g.y); wB[2 * q + 1] = pack2(g.z, g.w);
    }
  }

  for (int s = 0; s < TT + 2; ++s) {
    if (wid == 0) {
      if (s < TT) {
        // ---- layer0 closed loop: h0[s] from H0R[s-1] ----
        uint32_t h0v[16];
        load16(&H0R[(s - 1) & 3][0], h0v);
        float sA0 = xA[s & 3], sB0 = xB[s & 3];
        const int tp = (s + 4 < TT) ? (s + 4) : (TT - 1);
        xA[s & 3] = xgp[(size_t)tp * GG + gA];
        xB[s & 3] = xgp[(size_t)tp * GG + gB];
        float pA = 0.f, pB = 0.f;
#pragma unroll
        for (int k = 0; k < 16; k += 2) {
          sA0 = dot2(wA[k], h0v[k], sA0);
          pA  = dot2(wA[k + 1], h0v[k + 1], pA);
          sB0 = dot2(wB[k], h0v[k], sB0);
          pB  = dot2(wB[k + 1], h0v[k + 1], pB);
        }
        sA0 += pA; sB0 += pB;
        float aA = act_sel(sA0, hi != 0);
        float aB = sigm(sB0);
        float pAx = partner32(aA);
        float pBx = partner32(aB);
        float gi = hi ? pAx : aA;
        float gf = hi ? pBx : aB;
        float gg = hi ? aA : pAx;
        float go = hi ? aB : pBx;
        cc = fmaf(gf, cc, gi * gg);
        float h = go * fast_tanh(cc);
        float oth = xor1_dpp(h);
        float lo = (j & 1) ? oth : h;
        float hh = (j & 1) ? h : oth;
        uint32_t pk = pack2(lo, hh);
        if (wrt) H0R[s & 3][j >> 1] = pk;
      }
    } else if (wid == 1) {
      if (s >= 1 && s <= TT) {
        // ---- PIH[tau] = b1 + Wih1*h0[tau], tau = s-1 ----
        const int tau = s - 1;
        uint32_t h0v[16];
        load16(&H0R[tau & 3][0], h0v);
        float a0 = b1A, a1 = 0.f, b0 = b1B, b1v = 0.f;
#pragma unroll
        for (int k = 0; k < 16; k += 2) {
          a0 = dot2(wA[k], h0v[k], a0);
          a1 = dot2(wA[k + 1], h0v[k + 1], a1);
          b0 = dot2(wB[k], h0v[k], b0);
          b1v = dot2(wB[k + 1], h0v[k + 1], b1v);
        }
        PIA[tau & 3][l] = a0 + a1;
        PIB[tau & 3][l] = b0 + b1v;
      }
    } else {
      if (s >= 2) {
        // ---- layer1 closed loop for tau = s-2 ----
        const int tau = s - 2;
        uint32_t h1v[16];
        load16(&H1R[(tau - 1) & 3][0], h1v);
        float sA1 = PIA[tau & 3][l];
        float sB1 = PIB[tau & 3][l];
        float qA = 0.f, qB = 0.f;
#pragma unroll
        for (int k = 0; k < 16; k += 2) {
          sA1 = dot2(wA[k], h1v[k], sA1);
          qA  = dot2(wA[k + 1], h1v[k + 1], qA);
          sB1 = dot2(wB[k], h1v[k], sB1);
          qB  = dot2(wB[k + 1], h1v[k + 1], qB);
        }
        sA1 += qA; sB1 += qB;
        float aA = act_sel(sA1, hi != 0);
        float aB = sigm(sB1);
        float pAx = partner32(aA);
        float pBx = partner32(aB);
        float gi = hi ? pAx : aA;
        float gf = hi ? pBx : aB;
        float gg = hi ? aA : pAx;
        float go = hi ? aB : pBx;
        cc = fmaf(gf, cc, gi * gg);
        float h = go * fast_tanh(cc);
        if (!hi) outp[(size_t)tau * HH + j] = h;
        float oth = xor1_dpp(h);
        float lo = (j & 1) ? oth : h;
        float hh = (j & 1) ? h : oth;
        uint32_t pk = pack2(lo, hh);
        if (wrt) H1R[tau & 3][j >> 1] = pk;
      }
    }
    __syncthreads();
  }
}

extern "C" void kernel_launch(void* const* d_in, const int* in_sizes, int n_in,
                              void* d_out, int out_size, void* d_ws, size_t ws_size,
                              hipStream_t stream) {
  const float* x = (const float*)d_in[0];
  const float* Wih0 = (const float*)d_in[1];
  const float* Whh0 = (const float*)d_in[2];
  const float* bih0 = (const float*)d_in[3];
  const float* bhh0 = (const float*)d_in[4];
  const float* Wih1 = (const float*)d_in[5];
  const float* Whh1 = (const float*)d_in[6];
  const float* bih1 = (const float*)d_in[7];
  const float* bhh1 = (const float*)d_in[8];
  float* out = (float*)d_out;
  float* xg = (float*)d_ws;  // B*T*4H*4 = 33.5 MB scratch

  xg_gemm_mfma<<<dim3((BB * TT) / 128), dim3(256), 0, stream>>>(x, Wih0, bih0, bhh0, xg);
  lstm_scan_sys<<<dim3(BB), dim3(192), 0, stream>>>(xg, Whh0, Wih1, Whh1, bih1, bhh1, out);
}